// Round 2
// baseline (450.018 us; speedup 1.0000x reference)
//
#include <hip/hip_runtime.h>

// out = clip(x + noise, 0, 1) — pure memory-bound elementwise op.
// 50,331,648 fp32 elements: 604 MB logical traffic -> ~96 us floor at 6.3 TB/s.
//
// R1 baseline: 1 float4/thread, plain stores -> 141 us/dispatch at 2.86 TB/s,
// VALUBusy 2.8% — latency/MLP limited, not BW-saturated.
// This version:
//   * 4 float4s per thread, block-strided within a 1024-float4 tile
//     (coalesced; 8 independent global loads in flight before first use).
//   * hot kernel has no bounds checks (exact tiling; remainder kernels cover
//     any non-multiple sizes and do not launch at this shape).
//   * nontemporal stores for `out` — output is never re-read, keep it from
//     evicting the input streams out of the 256 MB L3 (L3 currently absorbs
//     ~half the input reads: FETCH was 201 MB vs 402 MB logical).
//   * R2 fix: __builtin_nontemporal_store requires a NATIVE vector type —
//     use ext_vector_type(4) float instead of HIP's float4 class.

typedef float f32x4 __attribute__((ext_vector_type(4)));

#define UNROLL 4
#define BLOCK 256
#define TILE (BLOCK * UNROLL)   // float4s per block

__global__ __launch_bounds__(BLOCK) void gaussian_noise_clip_main(
    const f32x4* __restrict__ x,
    const f32x4* __restrict__ noise,
    f32x4* __restrict__ out) {
    int base = blockIdx.x * TILE + threadIdx.x;   // < 2^31 at this size

    f32x4 a[UNROLL];
    f32x4 b[UNROLL];
#pragma unroll
    for (int u = 0; u < UNROLL; ++u) a[u] = x[base + u * BLOCK];
#pragma unroll
    for (int u = 0; u < UNROLL; ++u) b[u] = noise[base + u * BLOCK];

#pragma unroll
    for (int u = 0; u < UNROLL; ++u) {
        f32x4 r;
        r.x = fminf(fmaxf(a[u].x + b[u].x, 0.0f), 1.0f);
        r.y = fminf(fmaxf(a[u].y + b[u].y, 0.0f), 1.0f);
        r.z = fminf(fmaxf(a[u].z + b[u].z, 0.0f), 1.0f);
        r.w = fminf(fmaxf(a[u].w + b[u].w, 0.0f), 1.0f);
        __builtin_nontemporal_store(r, &out[base + u * BLOCK]);
    }
}

// Generic remainder kernel: float4 grid-stride starting at start4
// (not exercised at this size — n4 % TILE == 0 — kept for safety).
__global__ __launch_bounds__(BLOCK) void gaussian_noise_clip_rem4(
    const f32x4* __restrict__ x,
    const f32x4* __restrict__ noise,
    f32x4* __restrict__ out,
    int start4, int n4) {
    int i = start4 + blockIdx.x * blockDim.x + threadIdx.x;
    if (i < n4) {
        f32x4 a = x[i];
        f32x4 b = noise[i];
        f32x4 r;
        r.x = fminf(fmaxf(a.x + b.x, 0.0f), 1.0f);
        r.y = fminf(fmaxf(a.y + b.y, 0.0f), 1.0f);
        r.z = fminf(fmaxf(a.z + b.z, 0.0f), 1.0f);
        r.w = fminf(fmaxf(a.w + b.w, 0.0f), 1.0f);
        out[i] = r;
    }
}

// Scalar tail (n % 4 != 0; not exercised at this size).
__global__ __launch_bounds__(BLOCK) void gaussian_noise_clip_tail(
    const float* __restrict__ x,
    const float* __restrict__ noise,
    float* __restrict__ out,
    int start, int n) {
    int i = start + blockIdx.x * blockDim.x + threadIdx.x;
    if (i < n) {
        out[i] = fminf(fmaxf(x[i] + noise[i], 0.0f), 1.0f);
    }
}

extern "C" void kernel_launch(void* const* d_in, const int* in_sizes, int n_in,
                              void* d_out, int out_size, void* d_ws, size_t ws_size,
                              hipStream_t stream) {
    const float* x     = (const float*)d_in[0];
    const float* noise = (const float*)d_in[1];
    float* out         = (float*)d_out;

    int n  = in_sizes[0];      // 50,331,648 elements
    int n4 = n / 4;            // 12,582,912 float4s

    int ntiles = n4 / TILE;    // 12,288 full tiles — exact at this size
    if (ntiles > 0) {
        gaussian_noise_clip_main<<<ntiles, BLOCK, 0, stream>>>(
            (const f32x4*)x, (const f32x4*)noise, (f32x4*)out);
    }

    int done4 = ntiles * TILE;
    int rem4 = n4 - done4;
    if (rem4 > 0) {
        int rgrid = (rem4 + BLOCK - 1) / BLOCK;
        gaussian_noise_clip_rem4<<<rgrid, BLOCK, 0, stream>>>(
            (const f32x4*)x, (const f32x4*)noise, (f32x4*)out, done4, n4);
    }

    int tail_start = n4 * 4;
    int tail = n - tail_start;
    if (tail > 0) {
        int tgrid = (tail + BLOCK - 1) / BLOCK;
        gaussian_noise_clip_tail<<<tgrid, BLOCK, 0, stream>>>(
            x, noise, out, tail_start, n);
    }
}